// Round 6
// baseline (525.243 us; speedup 1.0000x reference)
//
#include <hip/hip_runtime.h>
#include <stdint.h>

// FlowNet correlation: out[b, dy*9+dx, y, x] = (1/256) sum_c x1[b,c,y,x] * x2[b,c,y+dy-4,x+dx-4]
// B=4 C=256 H=W=128, 9x9 displacements, zero padding.
//
// Round-6 design:
//  - PX=8 register blocking: tile 32x16, lane = (16 rows x 4 groups of 8 px).
//    Per cl: 4 x2 ds_read_b128 for 72 FMAs -> LDS:VALU 1:18 (was 1:9) -> LDS floor ~23 us.
//  - Channel split x2 (hf=0/1 each does 128 ch) to keep 768 blocks / 9 waves/CU;
//    halves combined via no-return global atomicAdd into memset-zeroed d_out.
//  - x1 via inline global loads (r4-validated; kills the r5 stride-16 LDS conflict).
//  - x2 rows padded to 44 dw (11 slots/row): (12*row + 8*grp) mod 32 -> uniform
//    8 dw/bank for every b128 -> conflict-free.
//  - Async global_load_lds staging, 3 buffers, distance-2, vmcnt(5) waits (r5 pattern);
//    k+2 issue AFTER compute so compiler x1-waits never force-drain prefetches.
//  - XCD swizzle: all 6 siblings (3 dy-groups x 2 halves) of a tile share an XCD L2.

#define MD 4
constexpr int Bc = 4, Cc = 256, Hc = 128, Wc = 128;
constexpr int HW = Hc * Wc;
constexpr int TW = 32, TH = 16;
constexpr int CC = 4;                      // channels per chunk
constexpr int NK = 32;                     // chunks (128 ch / 4)
constexpr int SROWS = 18;                  // 16 + 2 halo rows (3 dy per group)
constexpr int RSLOT = 11;                  // 10 data slots + 1 pad -> 44 dw row stride
constexpr int CH_SLOTS = SROWS * RSLOT;    // 198
constexpr int REAL_SLOTS = CC * CH_SLOTS;  // 792
constexpr int NTHR = 192;
constexpr int NSLOT = 5;                   // 960 slots staged per chunk (168 zpage pad)
constexpr int SLOTS = NTHR * NSLOT;        // 960
constexpr int BUF_DW = SLOTS * 4;          // 3840 dw = 15.36 KB per buffer
constexpr int CH_DW = CH_SLOTS * 4;        // 792 dw
constexpr int ROW_DW = RSLOT * 4;          // 44 dw

__device__ __forceinline__ void async16(const void* g, void* l) {
    __builtin_amdgcn_global_load_lds(
        (const __attribute__((address_space(1))) unsigned int*)g,
        (__attribute__((address_space(3))) unsigned int*)l, 16, 0, 0);
}

__global__ __launch_bounds__(NTHR, 3)
void corr_kernel(const float* __restrict__ x1, const float* __restrict__ x2,
                 const float* __restrict__ zpage, float* __restrict__ out)
{
    __shared__ float stg[3 * BUF_DW];   // 46080 B -> 3 blocks/CU

    const int tid  = threadIdx.x;
    const int w    = tid >> 6;          // wave id = local dy (0..2)
    const int lane = tid & 63;
    const int gy   = lane >> 2;         // 0..15 tile row
    const int gxg  = lane & 3;          // 0..3  8-px group

    // ---- XCD swizzle: 6 siblings of a tile at bids {base, base+8, ..., base+40} ----
    const int bid = blockIdx.x;
    const int q   = bid / 48;
    const int r0  = bid - q * 48;
    const int sib = r0 >> 3;            // 0..5
    const int t   = q * 8 + (r0 & 7);   // tile instance 0..127
    const int g   = sib % 3;            // dy group
    const int hf  = sib / 3;            // channel half
    const int tx = t & 3, ty = (t >> 2) & 7, bb = t >> 5;
    const int x0 = tx * TW, y0 = ty * TH;
    const int rowbase = y0 + 3 * g - MD;

    const size_t cbase = ((size_t)bb * Cc + hf * 128) * HW;

    // ---- staging slot descriptors (fixed per thread) ----
    const char* sp[NSLOT];
    int sstep[NSLOT], sloff[NSLOT];
    #pragma unroll
    for (int s = 0; s < NSLOT; ++s) {
        const int slot = tid + s * NTHR;
        sloff[s] = slot * 4;
        const char* src = (const char*)zpage;
        int step = 0;
        if (slot < REAL_SLOTS) {
            const int cl  = slot / CH_SLOTS;
            const int rem = slot - cl * CH_SLOTS;
            const int rr  = rem / RSLOT;
            const int sl  = rem - rr * RSLOT;
            if (sl < 10) {
                const int yy = rowbase + rr;
                const int xx = x0 - 4 + 4 * sl;
                if ((unsigned)yy < (unsigned)Hc && (unsigned)xx <= (unsigned)(Wc - 4)) {
                    src  = (const char*)(x2 + cbase + (size_t)cl * HW + yy * Wc + xx);
                    step = (int)(CC * HW * sizeof(float));
                }
            }
        }
        sp[s] = src;  sstep[s] = step;
    }

    const float* x1b = x1 + cbase + (y0 + gy) * Wc + x0 + 8 * gxg;

    float acc[9][8];
    #pragma unroll
    for (int dx = 0; dx < 9; ++dx)
        #pragma unroll
        for (int p = 0; p < 8; ++p) acc[dx][p] = 0.f;

    // ---- prologue: issue chunks 0 and 1 ----
    #pragma unroll
    for (int s = 0; s < NSLOT; ++s) {
        async16(sp[s], (void*)(&stg[0 * BUF_DW] + sloff[s]));
        sp[s] += sstep[s];
    }
    #pragma unroll
    for (int s = 0; s < NSLOT; ++s) {
        async16(sp[s], (void*)(&stg[1 * BUF_DW] + sloff[s]));
        sp[s] += sstep[s];
    }

    int bc = 0;   // k % 3
    for (int k = 0; k < NK; ++k) {
        // drain chunk k's async loads (in-order vmcnt: oldest 5 of 10 outstanding)
        if (k == NK - 1) __builtin_amdgcn_s_waitcnt(0x0F70);   // vmcnt(0)
        else             __builtin_amdgcn_s_waitcnt(0x0F75);   // vmcnt(5)
        __builtin_amdgcn_s_barrier();
        __builtin_amdgcn_sched_barrier(0);

        // ---- compute chunk k: x2 from LDS, x1 inline from global (L2-hot) ----
        const float* bp = &stg[bc * BUF_DW];
        #pragma unroll
        for (int cl = 0; cl < CC; ++cl) {
            const float* ap = x1b + (size_t)(k * CC + cl) * HW;
            const float4 A0 = *(const float4*)(ap);
            const float4 A1 = *(const float4*)(ap + 4);
            const float* rowp = bp + cl * CH_DW + (gy + w) * ROW_DW + 8 * gxg;
            const float4 q0 = *(const float4*)(rowp);
            const float4 q1 = *(const float4*)(rowp + 4);
            const float4 q2 = *(const float4*)(rowp + 8);
            const float4 q3 = *(const float4*)(rowp + 12);
            const float v[16] = {q0.x, q0.y, q0.z, q0.w, q1.x, q1.y, q1.z, q1.w,
                                 q2.x, q2.y, q2.z, q2.w, q3.x, q3.y, q3.z, q3.w};
            const float a[8] = {A0.x, A0.y, A0.z, A0.w, A1.x, A1.y, A1.z, A1.w};
            #pragma unroll
            for (int dx = 0; dx < 9; ++dx)
                #pragma unroll
                for (int p = 0; p < 8; ++p)
                    acc[dx][p] += a[p] * v[p + dx];
        }
        __builtin_amdgcn_sched_barrier(0);

        // ---- issue chunk k+2 (buffer last read as chunk k-1: safe post-barrier) ----
        if (k + 2 < NK) {
            int b2 = bc + 2; if (b2 >= 3) b2 -= 3;
            float* bp2 = &stg[b2 * BUF_DW];
            #pragma unroll
            for (int s = 0; s < NSLOT; ++s) {
                async16(sp[s], (void*)(bp2 + sloff[s]));
                sp[s] += sstep[s];
            }
        }
        __builtin_amdgcn_sched_barrier(0);
        if (++bc == 3) bc = 0;
    }

    // ---- epilogue: no-return atomic adds combine the two channel halves ----
    const float inv = 1.0f / (float)Cc;
    float* ob = out + (((size_t)bb * 81 + (3 * g + w) * 9) * Hc + (y0 + gy)) * Wc + x0 + 8 * gxg;
    #pragma unroll
    for (int dx = 0; dx < 9; ++dx) {
        float* od = ob + (size_t)dx * HW;
        #pragma unroll
        for (int p = 0; p < 8; ++p)
            atomicAdd(od + p, acc[dx][p] * inv);
    }
}

extern "C" void kernel_launch(void* const* d_in, const int* in_sizes, int n_in,
                              void* d_out, int out_size, void* d_ws, size_t ws_size,
                              hipStream_t stream) {
    const float* x1 = (const float*)d_in[0];
    const float* x2 = (const float*)d_in[1];
    float* out = (float*)d_out;
    // d_out is poisoned each launch: zero it (atomics accumulate into it).
    hipMemsetAsync(d_out, 0, (size_t)out_size * sizeof(float), stream);
    // 64-B zero page for OOB/pad staging sources.
    hipMemsetAsync(d_ws, 0, 64, stream);
    dim3 grid(4 * 8 * 4 * 6), block(NTHR);   // 768 blocks (128 tiles x 3 dy-groups x 2 halves)
    corr_kernel<<<grid, block, 0, stream>>>(x1, x2, (const float*)d_ws, out);
}

// Round 7
// 446.440 us; speedup vs baseline: 1.1765x; 1.1765x over previous
//
#include <hip/hip_runtime.h>
#include <stdint.h>

// FlowNet correlation: out[b, dy*9+dx, y, x] = (1/256) sum_c x1[b,c,y,x] * x2[b,c,y+dy-4,x+dx-4]
// B=4 C=256 H=W=128, 9x9 displacements, zero padding.
//
// Round-7 = round-6 with ONE change: __launch_bounds__(192, 1).
// Empirical allocator law from r2-r6: with (192, minW) the compiler caps VGPRs at
// 512/(2*minW) and spills rather than exceed it. r6's (192,3) -> 84-VGPR cap spilled
// the 72-reg accumulator to scratch (WRITE_SIZE 448 MB, VALUBusy 6%). (192,1) -> cap
// 256, fits the ~130 live regs. Occupancy remains LDS-bound at 3 blocks/CU regardless.
//
//  - PX=8 register blocking: tile 32x16, lane = (16 rows x 4 groups of 8 px).
//    Per cl: 4 x2 ds_read_b128 for 72 FMAs -> LDS floor ~23 us, VALU ~17 us.
//  - Channel split x2 (hf=0/1 each does 128 ch); halves combined via no-return
//    global atomicAdd into memset-zeroed d_out.
//  - x1 via inline global loads (L2-hot, r4-validated).
//  - x2 rows padded to 44 dw: (12*gy + 8*gxg) mod 32 covers all 32 banks per
//    8-lane phase -> compute reads conflict-free; staging writes lane-contiguous.
//  - Async global_load_lds staging, 3 buffers, distance-2, vmcnt(5) waits;
//    uniform 5 slots/thread (zpage-padded) for deterministic vmcnt.
//  - XCD swizzle: all 6 siblings (3 dy-groups x 2 halves) of a tile share an XCD L2
//    (validated: FETCH 464 -> ~190 MB).

#define MD 4
constexpr int Bc = 4, Cc = 256, Hc = 128, Wc = 128;
constexpr int HW = Hc * Wc;
constexpr int TW = 32, TH = 16;
constexpr int CC = 4;                      // channels per chunk
constexpr int NK = 32;                     // chunks (128 ch / 4)
constexpr int SROWS = 18;                  // 16 + 2 halo rows (3 dy per group)
constexpr int RSLOT = 11;                  // 10 data slots + 1 pad -> 44 dw row stride
constexpr int CH_SLOTS = SROWS * RSLOT;    // 198
constexpr int REAL_SLOTS = CC * CH_SLOTS;  // 792
constexpr int NTHR = 192;
constexpr int NSLOT = 5;                   // 960 slots staged per chunk (168 zpage pad)
constexpr int SLOTS = NTHR * NSLOT;        // 960
constexpr int BUF_DW = SLOTS * 4;          // 3840 dw = 15.36 KB per buffer
constexpr int CH_DW = CH_SLOTS * 4;        // 792 dw
constexpr int ROW_DW = RSLOT * 4;          // 44 dw

__device__ __forceinline__ void async16(const void* g, void* l) {
    __builtin_amdgcn_global_load_lds(
        (const __attribute__((address_space(1))) unsigned int*)g,
        (__attribute__((address_space(3))) unsigned int*)l, 16, 0, 0);
}

__global__ __launch_bounds__(NTHR, 1)
void corr_kernel(const float* __restrict__ x1, const float* __restrict__ x2,
                 const float* __restrict__ zpage, float* __restrict__ out)
{
    __shared__ float stg[3 * BUF_DW];   // 46080 B -> 3 blocks/CU (LDS-bound)

    const int tid  = threadIdx.x;
    const int w    = tid >> 6;          // wave id = local dy (0..2)
    const int lane = tid & 63;
    const int gy   = lane >> 2;         // 0..15 tile row
    const int gxg  = lane & 3;          // 0..3  8-px group

    // ---- XCD swizzle: 6 siblings of a tile at bids {base, base+8, ..., base+40} ----
    const int bid = blockIdx.x;
    const int q   = bid / 48;
    const int r0  = bid - q * 48;
    const int sib = r0 >> 3;            // 0..5
    const int t   = q * 8 + (r0 & 7);   // tile instance 0..127
    const int g   = sib % 3;            // dy group
    const int hf  = sib / 3;            // channel half
    const int tx = t & 3, ty = (t >> 2) & 7, bb = t >> 5;
    const int x0 = tx * TW, y0 = ty * TH;
    const int rowbase = y0 + 3 * g - MD;

    const size_t cbase = ((size_t)bb * Cc + hf * 128) * HW;

    // ---- staging slot descriptors (fixed per thread) ----
    const char* sp[NSLOT];
    int sstep[NSLOT], sloff[NSLOT];
    #pragma unroll
    for (int s = 0; s < NSLOT; ++s) {
        const int slot = tid + s * NTHR;
        sloff[s] = slot * 4;
        const char* src = (const char*)zpage;
        int step = 0;
        if (slot < REAL_SLOTS) {
            const int cl  = slot / CH_SLOTS;
            const int rem = slot - cl * CH_SLOTS;
            const int rr  = rem / RSLOT;
            const int sl  = rem - rr * RSLOT;
            if (sl < 10) {
                const int yy = rowbase + rr;
                const int xx = x0 - 4 + 4 * sl;
                if ((unsigned)yy < (unsigned)Hc && (unsigned)xx <= (unsigned)(Wc - 4)) {
                    src  = (const char*)(x2 + cbase + (size_t)cl * HW + yy * Wc + xx);
                    step = (int)(CC * HW * sizeof(float));
                }
            }
        }
        sp[s] = src;  sstep[s] = step;
    }

    const float* x1b = x1 + cbase + (y0 + gy) * Wc + x0 + 8 * gxg;

    float acc[9][8];
    #pragma unroll
    for (int dx = 0; dx < 9; ++dx)
        #pragma unroll
        for (int p = 0; p < 8; ++p) acc[dx][p] = 0.f;

    // ---- prologue: issue chunks 0 and 1 ----
    #pragma unroll
    for (int s = 0; s < NSLOT; ++s) {
        async16(sp[s], (void*)(&stg[0 * BUF_DW] + sloff[s]));
        sp[s] += sstep[s];
    }
    #pragma unroll
    for (int s = 0; s < NSLOT; ++s) {
        async16(sp[s], (void*)(&stg[1 * BUF_DW] + sloff[s]));
        sp[s] += sstep[s];
    }

    int bc = 0;   // k % 3
    for (int k = 0; k < NK; ++k) {
        // drain chunk k's async loads (in-order vmcnt: oldest 5 of 10 outstanding)
        if (k == NK - 1) __builtin_amdgcn_s_waitcnt(0x0F70);   // vmcnt(0)
        else             __builtin_amdgcn_s_waitcnt(0x0F75);   // vmcnt(5)
        __builtin_amdgcn_s_barrier();
        __builtin_amdgcn_sched_barrier(0);

        // ---- compute chunk k: x2 from LDS, x1 inline from global (L2-hot) ----
        const float* bp = &stg[bc * BUF_DW];
        #pragma unroll
        for (int cl = 0; cl < CC; ++cl) {
            const float* ap = x1b + (size_t)(k * CC + cl) * HW;
            const float4 A0 = *(const float4*)(ap);
            const float4 A1 = *(const float4*)(ap + 4);
            const float* rowp = bp + cl * CH_DW + (gy + w) * ROW_DW + 8 * gxg;
            const float4 q0 = *(const float4*)(rowp);
            const float4 q1 = *(const float4*)(rowp + 4);
            const float4 q2 = *(const float4*)(rowp + 8);
            const float4 q3 = *(const float4*)(rowp + 12);
            const float v[16] = {q0.x, q0.y, q0.z, q0.w, q1.x, q1.y, q1.z, q1.w,
                                 q2.x, q2.y, q2.z, q2.w, q3.x, q3.y, q3.z, q3.w};
            const float a[8] = {A0.x, A0.y, A0.z, A0.w, A1.x, A1.y, A1.z, A1.w};
            #pragma unroll
            for (int dx = 0; dx < 9; ++dx)
                #pragma unroll
                for (int p = 0; p < 8; ++p)
                    acc[dx][p] += a[p] * v[p + dx];
        }
        __builtin_amdgcn_sched_barrier(0);

        // ---- issue chunk k+2 (buffer last read as chunk k-1: safe post-barrier) ----
        if (k + 2 < NK) {
            int b2 = bc + 2; if (b2 >= 3) b2 -= 3;
            float* bp2 = &stg[b2 * BUF_DW];
            #pragma unroll
            for (int s = 0; s < NSLOT; ++s) {
                async16(sp[s], (void*)(bp2 + sloff[s]));
                sp[s] += sstep[s];
            }
        }
        __builtin_amdgcn_sched_barrier(0);
        if (++bc == 3) bc = 0;
    }

    // ---- epilogue: no-return atomic adds combine the two channel halves ----
    const float inv = 1.0f / (float)Cc;
    float* ob = out + (((size_t)bb * 81 + (3 * g + w) * 9) * Hc + (y0 + gy)) * Wc + x0 + 8 * gxg;
    #pragma unroll
    for (int dx = 0; dx < 9; ++dx) {
        float* od = ob + (size_t)dx * HW;
        #pragma unroll
        for (int p = 0; p < 8; ++p)
            atomicAdd(od + p, acc[dx][p] * inv);
    }
}

extern "C" void kernel_launch(void* const* d_in, const int* in_sizes, int n_in,
                              void* d_out, int out_size, void* d_ws, size_t ws_size,
                              hipStream_t stream) {
    const float* x1 = (const float*)d_in[0];
    const float* x2 = (const float*)d_in[1];
    float* out = (float*)d_out;
    // d_out is poisoned each launch: zero it (atomics accumulate into it).
    hipMemsetAsync(d_out, 0, (size_t)out_size * sizeof(float), stream);
    // 64-B zero page for OOB/pad staging sources.
    hipMemsetAsync(d_ws, 0, 64, stream);
    dim3 grid(4 * 8 * 4 * 6), block(NTHR);   // 768 blocks (128 tiles x 3 dy-groups x 2 halves)
    corr_kernel<<<grid, block, 0, stream>>>(x1, x2, (const float*)d_ws, out);
}

// Round 8
// 364.237 us; speedup vs baseline: 1.4420x; 1.2257x over previous
//
#include <hip/hip_runtime.h>
#include <stdint.h>

// FlowNet correlation via banded MFMA GEMM (bf16 inputs, fp32 acc).
// out[b, dy*9+dx, y, x] = (1/256) sum_c x1[b,c,y,x] * x2[b,c,y+dy-4,x+dx-4]
//
// Per (b, y, dy): D[m,n] = sum_c x1[c, x0+m] * x2row[c, x0-4+n]; out dx = n-m in [0,8].
// 16x16x32 bf16 MFMA, 2 n-tiles (n0 = x0-4, x0+12) cover the 9-diagonal band.
// Block = 384 thr = 6 waves = (3 local dy) x (2 y-halves) on a 16x16 (y,x) tile.
// Wave: 1 dy, 8 y, 2 n-tiles -> acc 8*2*f32x4 = 64 VGPRs (fits the 128 ceiling
// this compiler enforces; r6/r7 showed vector-ALU PX=8 cannot).
// LDS: k-major bf16, pitch 40 (80 B) -> b128 frag reads 16B-aligned and 2-way
// bank-free; staging = global fp32 -> RNE bf16 -> ds_write_b64 (4-way, minor).
// XCD swizzle kept (r4-validated: g-siblings share XCD L2).

typedef __attribute__((ext_vector_type(8))) short short8;
typedef __attribute__((ext_vector_type(4))) float f32x4;

constexpr int Bc = 4, Cc = 256, Hc = 128, Wc = 128;
constexpr int HW = Hc * Wc;
constexpr int TW = 16, TH = 16;
constexpr int KP = 40;             // shorts per (row,col) k-vector: 32 ch + 8 pad
constexpr int NTHR = 384;
constexpr int NKS = 8;             // 256 ch / 32 per MFMA k-step

__device__ __forceinline__ unsigned f2bf(float f) {
    unsigned u = __float_as_uint(f);
    return (u + 0x7fffu + ((u >> 16) & 1u)) >> 16;   // round-to-nearest-even bf16
}

__global__ __launch_bounds__(NTHR, 1)
void corr_mfma(const float* __restrict__ x1, const float* __restrict__ x2,
               float* __restrict__ out)
{
    __shared__ __align__(16) unsigned short x1s[256 * KP];  // [y16][x16][k 40]
    __shared__ __align__(16) unsigned short x2s[576 * KP];  // [r18][col32][k 40]

    const int tid  = threadIdx.x;
    const int w    = tid >> 6;
    const int lane = tid & 63;
    const int quad = lane >> 4;
    const int cl   = lane & 15;
    const int d    = w >> 1;       // local dy 0..2
    const int yh   = w & 1;        // y-half 0..1

    // ---- XCD swizzle: 3 g-siblings of a tile at bids {base, base+8, base+16} ----
    const int bid = blockIdx.x;
    const int q   = bid / 24;
    const int r0  = bid - q * 24;
    const int g   = r0 >> 3;
    const int t   = q * 8 + (r0 & 7);
    const int tx = t & 7, ty = (t >> 3) & 7, bb = t >> 6;
    const int x0 = tx * TW, y0 = ty * TH;
    const int rowbase = y0 + 3 * g - 4;    // global y of x2 LDS row 0

    const float* x1b = x1 + (size_t)bb * Cc * HW;
    const float* x2b = x2 + (size_t)bb * Cc * HW;

    f32x4 acc[8][2];
    #pragma unroll
    for (int i = 0; i < 8; ++i) { acc[i][0] = (f32x4)0.f; acc[i][1] = (f32x4)0.f; }

    for (int ks = 0; ks < NKS; ++ks) {
        const int kc = ks * 32;
        __syncthreads();   // previous k-step's fragment readers done
        // ---- stage x2: 4608 units (kq, r, col), 12 per thread; col = lane-consecutive ----
        #pragma unroll 4
        for (int j = 0; j < 12; ++j) {
            const int u   = tid + j * NTHR;
            const int kq  = u / 576;
            const int rem = u - kq * 576;
            const int rr  = rem >> 5;
            const int col = rem & 31;
            const int gy  = rowbase + rr;
            const int gx  = x0 - 4 + col;
            const bool v  = ((unsigned)gy < (unsigned)Hc) && ((unsigned)gx < (unsigned)Wc);
            const float* p = x2b + (size_t)(kc + kq * 4) * HW + gy * Wc + gx;
            const float f0 = v ? p[0] : 0.f;
            const float f1 = v ? p[HW] : 0.f;
            const float f2 = v ? p[2 * HW] : 0.f;
            const float f3 = v ? p[3 * HW] : 0.f;
            const unsigned lo = f2bf(f0) | (f2bf(f1) << 16);
            const unsigned hi = f2bf(f2) | (f2bf(f3) << 16);
            *(uint2*)&x2s[(rr * 32 + col) * KP + kq * 4] = make_uint2(lo, hi);
        }
        // ---- stage x1: 2048 units (kq, y, x), <=6 per thread ----
        #pragma unroll
        for (int j = 0; j < 6; ++j) {
            const int u = tid + j * NTHR;
            if (u < 2048) {
                const int kq = u >> 8, yy = (u >> 4) & 15, xx = u & 15;
                const float* p = x1b + (size_t)(kc + kq * 4) * HW + (y0 + yy) * Wc + x0 + xx;
                const unsigned lo = f2bf(p[0]) | (f2bf(p[HW]) << 16);
                const unsigned hi = f2bf(p[2 * HW]) | (f2bf(p[3 * HW]) << 16);
                *(uint2*)&x1s[(yy * 16 + xx) * KP + kq * 4] = make_uint2(lo, hi);
            }
        }
        __syncthreads();   // tiles staged
        // ---- compute: per wave 8 y x 2 n-tiles = 16 MFMAs per k-step ----
        #pragma unroll
        for (int yy = 0; yy < 8; ++yy) {
            const int ylds = yh * 8 + yy;
            const int rr   = ylds + d;            // x2 LDS row for (y, dy)
            const short8 a  = *(const short8*)&x1s[(ylds * 16 + cl) * KP + quad * 8];
            const short8 b0 = *(const short8*)&x2s[(rr * 32 + cl) * KP + quad * 8];
            const short8 b1 = *(const short8*)&x2s[(rr * 32 + 16 + cl) * KP + quad * 8];
            acc[yy][0] = __builtin_amdgcn_mfma_f32_16x16x32_bf16(a, b0, acc[yy][0], 0, 0, 0);
            acc[yy][1] = __builtin_amdgcn_mfma_f32_16x16x32_bf16(a, b1, acc[yy][1], 0, 0, 0);
        }
    }

    // ---- epilogue: D[m = quad*4+i][n]; dx = n_loc - m; predicated scalar stores ----
    const float inv = 1.0f / (float)Cc;
    const int dy = 3 * g + d;
    #pragma unroll
    for (int yy = 0; yy < 8; ++yy) {
        const int gyy = y0 + yh * 8 + yy;
        #pragma unroll
        for (int nt = 0; nt < 2; ++nt) {
            const int nloc = cl + 16 * nt;
            #pragma unroll
            for (int i = 0; i < 4; ++i) {
                const int m  = quad * 4 + i;
                const int dx = nloc - m;
                if ((unsigned)dx < 9u) {
                    out[(((size_t)bb * 81 + dy * 9 + dx) * Hc + gyy) * Wc + x0 + m] =
                        acc[yy][nt][i] * inv;
                }
            }
        }
    }
}

extern "C" void kernel_launch(void* const* d_in, const int* in_sizes, int n_in,
                              void* d_out, int out_size, void* d_ws, size_t ws_size,
                              hipStream_t stream) {
    const float* x1 = (const float*)d_in[0];
    const float* x2 = (const float*)d_in[1];
    float* out = (float*)d_out;
    dim3 grid(3 * 8 * 8 * Bc), block(NTHR);   // 768 blocks x 384 threads
    corr_mfma<<<grid, block, 0, stream>>>(x1, x2, out);
}